// Round 8
// baseline (603.376 us; speedup 1.0000x reference)
//
#include <hip/hip_runtime.h>
#include <hip/hip_bf16.h>

// GraphLSTM: B=128, S=128, N=24, F=16, H=32 -> IS=384, HS=768, gates=3072.
// R15 = R14 (573us: phase-split, dbuf x, conflict-free pitch) with the
// exchange decoupled to WAVE grain:
//  * flags are per-(team,wg,wave): each wave stores its 64 exchange dwords,
//    drains ITS OWN vmcnt (inline s_waitcnt -- same visibility mechanism the
//    proven sync(a) path used block-wide), fires its own flag line. No block
//    barrier before publication.
//  * each consumer wave needs h cols only from producers 6wv..6wv+5
//    (du/8 == wg): it polls those 24 wave-flags (lanes 0..23), loads its
//    768-u64 quarter into REGISTERS, then sync(a) -> ds_write -> sync(b).
//    sync(a) protects the h-LDS WAR (every wave's phase-B reads precede its
//    flag store by program order; all waves must arrive before any write).
//  * early waves' flag RTT + data loads overlap the straggler; phase A /
//    x-stage / out stores fill each wave's own drain window.
// Accumulation order unchanged (kk ascending) -> same absmax.

typedef __bf16 bf16x8 __attribute__((ext_vector_type(8)));
typedef float f32x4 __attribute__((ext_vector_type(4)));

#define HS 768
#define GATES 3072
#define KV 1152          // combined K: 384 (W) + 768 (U)
#define SEQ 128
#define BATCH 128
#define OUT_HID (BATCH*SEQ*HS)
#define LROW 3120        // LDS row pitch (bytes); /16 % 8 == 3 -> even spread
#define HOFF 1536        // h region offset within a row
#define NWG 192
#define TEAM_WGS 24

__device__ __forceinline__ float fast_sig(float x) {
    return 1.0f / (1.0f + __expf(-x));
}
__device__ __forceinline__ float fast_tanh(float x) {
    x = fminf(fmaxf(x, -15.0f), 15.0f);
    float e = __expf(2.0f * x);
    return (e - 1.0f) / (e + 1.0f);
}

// convert 8 consecutive fp32 -> bf16x8 (RNE via cast)
__device__ __forceinline__ bf16x8 cvt8(const float* src) {
    float4 v0 = *(const float4*)src;
    float4 v1 = *(const float4*)(src + 4);
    bf16x8 p;
    p[0] = (__bf16)v0.x; p[1] = (__bf16)v0.y; p[2] = (__bf16)v0.z; p[3] = (__bf16)v0.w;
    p[4] = (__bf16)v1.x; p[5] = (__bf16)v1.y; p[6] = (__bf16)v1.z; p[7] = (__bf16)v1.w;
    return p;
}

// ---------------------------------------------------------------------------
// Kernel 1: masked + transposed weights (fp32 in, bf16 out).   [R4-validated]
// ---------------------------------------------------------------------------
__global__ void prep_kernel(const float* __restrict__ W, const float* __restrict__ U,
                            const float* __restrict__ G, __bf16* __restrict__ VmT) {
    __shared__ __bf16 tile[64][65];
    const int kvb = blockIdx.x * 64;
    const int cb  = blockIdx.y * 64;
    const int tid = threadIdx.x;
    {
        const int cl = tid & 63, kl0 = tid >> 6;
        #pragma unroll
        for (int i = 0; i < 16; ++i) {
            int kl = kl0 + i * 4;
            int kv = kvb + kl;
            int c  = cb + cl;
            int nout = (c % HS) >> 5;
            float g, v;
            if (kv < 384) {
                g = G[(kv >> 4) * 24 + nout];
                v = W[(size_t)kv * GATES + c];
            } else {
                int ku = kv - 384;
                g = G[(ku >> 5) * 24 + nout];
                v = U[(size_t)ku * GATES + c];
            }
            tile[kl][cl] = (__bf16)(v * g);
        }
    }
    __syncthreads();
    {
        const int kl = tid & 63, cl0 = tid >> 6;
        #pragma unroll
        for (int i = 0; i < 16; ++i) {
            int c = cl0 + i * 4;
            VmT[(size_t)(cb + c) * KV + kvb + kl] = tile[kl][c];
        }
    }
}

// ---------------------------------------------------------------------------
// Kernel 2: x fp32 [b][t][384] -> bf16 [t][b][384]
// ---------------------------------------------------------------------------
__global__ void prep_x(const float* __restrict__ x, __bf16* __restrict__ xb) {
    const int g = blockIdx.x * 256 + threadIdx.x;
    const int e = g * 8;
    const int b = e / (SEQ * 384);
    const int rem = e - b * (SEQ * 384);
    const int t = rem / 384;
    const int k = rem - t * 384;
    *(bf16x8*)&xb[((size_t)t * BATCH + b) * 384 + k] = cvt8(&x[e]);
}

// ---------------------------------------------------------------------------
// Kernel 3: persistent scan. 8 teams x 24 WGs = 192 WGs, 1 WG/CU.
// bar layout (64 KB, zeroed per launch):
//   flags: u32[8][24][4][16] -- one 64B line per (team,wg,wave), value = t+1
// Per step (per wave): phase B MFMA -> LSTM -> exchange store -> own vmcnt
// drain -> own flag store -> out stores -> phase A (x-part, LDS dbuf) ->
// stage x_{t+2} quarter -> poll 6 producers x 4 waves (lanes 0..23) ->
// load own 768-u64 h quarter to regs -> sync(a) -> ds_write -> sync(b).
// ---------------------------------------------------------------------------
__global__ __launch_bounds__(256, 1) void scan_kernel(
        const __bf16* __restrict__ xb,     // [t][b][384] bf16
        const float* __restrict__ h0,
        const float* __restrict__ c0,
        const __bf16* __restrict__ VmT,    // [3072][1152] bf16
        const float* __restrict__ bias,
        float* out,
        unsigned* xh32,                    // [2][128][384] packed bf16 pairs
        unsigned* bar) {
    __shared__ __align__(16) char Bs[16 * LROW];   // 49920 B
    const int tid = threadIdx.x;
    const int lane = tid & 63, wv = tid >> 6;
    const int m = lane & 15, quad = lane >> 4;
    const int team = blockIdx.x & 7, wg = blockIdx.x >> 3;
    const int bbase = team * 16;
    const int jbase = wg * 32 + wv * 8;

    unsigned* flags = bar;                              // [8][24][4][16]
    unsigned* myflag = flags + ((team * TEAM_WGS + wg) * 4 + wv) * 16;
    // consumer wave wv's producer-wave flag (lanes 0..23):
    const unsigned* pollflag = flags +
        ((team * TEAM_WGS + (6 * wv + (lane >> 2))) * 4 + (lane & 3)) * 16;

    // --- weights -> registers (read VmT exactly once for the whole scan) ---
    bf16x8 w[2][36];
    #pragma unroll
    for (int T = 0; T < 2; ++T) {
        const int cg = (m & 3) * HS + jbase + 2 * (m >> 2) + T;
        const __bf16* wp = VmT + (size_t)cg * KV;
        #pragma unroll
        for (int kk = 0; kk < 36; ++kk)
            w[T][kk] = *(const bf16x8*)(wp + kk * 32 + quad * 8);
    }

    const int b_own = bbase + m;
    const int j0 = jbase + 2 * quad;       // even
    const int j1 = j0 + 1;                 // odd (adjacent -> one u32)
    float cv0 = c0[b_own * HS + j0];
    float cv1 = c0[b_own * HS + j1];
    f32x4 bias0, bias1;
    #pragma unroll
    for (int r = 0; r < 4; ++r) {
        bias0[r] = bias[r * HS + j0];
        bias1[r] = bias[r * HS + j1];
    }

    // --- pre-loop staging: x_0 -> buf0, x_1 -> buf1, h0 -> h region ---
    #pragma unroll
    for (int i = 0; i < 3; ++i) {
        int ch = tid + i * 256;            // 768 x-chunks (16B)
        int row = ch / 48, c8 = ch % 48;
        *(uint4*)(Bs + row * LROW + c8 * 16) =
            *(const uint4*)&xb[((size_t)0 * BATCH + bbase + row) * 384 + c8 * 8];
        *(uint4*)(Bs + row * LROW + 768 + c8 * 16) =
            *(const uint4*)&xb[((size_t)1 * BATCH + bbase + row) * 384 + c8 * 8];
    }
    #pragma unroll
    for (int i = 0; i < 6; ++i) {
        int ch = tid + i * 256;            // 1536 h-chunks (bf16x8)
        int row = ch / 96, c8h = ch % 96;
        bf16x8 p = cvt8(&h0[(size_t)(bbase + row) * HS + c8h * 8]);
        *(bf16x8*)(Bs + row * LROW + HOFF + c8h * 16) = p;
    }
    __syncthreads();

    // --- phase A for step 0: bias + x-part (kk 0..11) from buf0 ---
    f32x4 accA0 = bias0, accA1 = bias1;
    {
        const char* xf = Bs + m * LROW + quad * 16;
        #pragma unroll
        for (int kk = 0; kk < 12; ++kk) {
            bf16x8 bf = *(const bf16x8*)(xf + kk * 64);
            accA0 = __builtin_amdgcn_mfma_f32_16x16x32_bf16(w[0][kk], bf, accA0, 0, 0, 0);
            accA1 = __builtin_amdgcn_mfma_f32_16x16x32_bf16(w[1][kk], bf, accA1, 0, 0, 0);
        }
    }

    #pragma unroll 1
    for (int t = 0; t < SEQ; ++t) {
        // phase B: h-part (kk 12..35) from LDS h region
        f32x4 acc0 = accA0, acc1 = accA1;
        const char* hf = Bs + m * LROW + HOFF + quad * 16;
        #pragma unroll
        for (int p = 0; p < 24; ++p) {
            bf16x8 bf = *(const bf16x8*)(hf + p * 64);
            acc0 = __builtin_amdgcn_mfma_f32_16x16x32_bf16(w[0][12 + p], bf, acc0, 0, 0, 0);
            acc1 = __builtin_amdgcn_mfma_f32_16x16x32_bf16(w[1][12 + p], bf, acc1, 0, 0, 0);
        }

        // LSTM elementwise (lane-local: acc reg index == gate i,f,g,o)
        float h0v, h1v;
        {
            float ii = fast_sig(acc0[0]), ff = fast_sig(acc0[1]);
            float gg = fast_tanh(acc0[2]), oo = fast_sig(acc0[3]);
            cv0 = ff * cv0 + ii * gg;
            h0v = oo * fast_tanh(cv0);
        }
        {
            float ii = fast_sig(acc1[0]), ff = fast_sig(acc1[1]);
            float gg = fast_tanh(acc1[2]), oo = fast_sig(acc1[3]);
            cv1 = ff * cv1 + ii * gg;
            h1v = oo * fast_tanh(cv1);
        }

        if (t == SEQ - 1) {
            const size_t obase = ((size_t)b_own * SEQ + t) * HS;
            *(float2*)&out[obase + j0] = make_float2(h0v, h1v);
            *(float2*)&out[OUT_HID + b_own * HS + j0] = make_float2(h0v, h1v);
            *(float2*)&out[OUT_HID + BATCH * HS + b_own * HS + j0] = make_float2(cv0, cv1);
            break;
        }

        // exchange store -> own-wave drain -> own flag (wave-grain publish)
        {
            unsigned lo = (unsigned)__builtin_bit_cast(unsigned short, (__bf16)h0v);
            unsigned hi = (unsigned)__builtin_bit_cast(unsigned short, (__bf16)h1v);
            unsigned* dst = xh32 + ((size_t)(t & 1) * BATCH + b_own) * 384
                                 + (jbase >> 1) + quad;
            __hip_atomic_store(dst, lo | (hi << 16), __ATOMIC_RELAXED,
                               __HIP_MEMORY_SCOPE_AGENT);
        }
        asm volatile("s_waitcnt vmcnt(0)" ::: "memory");   // own 64 dwords acked
        if (lane == 0)
            __hip_atomic_store(myflag, (unsigned)(t + 1), __ATOMIC_RELAXED,
                               __HIP_MEMORY_SCOPE_AGENT);

        // out stores: latency lands in this wave's poll window
        {
            const size_t obase = ((size_t)b_own * SEQ + t) * HS;
            *(float2*)&out[obase + j0] = make_float2(h0v, h1v);
        }

        // phase A for step t+1: bias + x-part from the other LDS x buffer
        accA0 = bias0; accA1 = bias1;
        {
            const char* xf = Bs + m * LROW + (((t + 1) & 1) ? 768 : 0) + quad * 16;
            #pragma unroll
            for (int kk = 0; kk < 12; ++kk) {
                bf16x8 bf = *(const bf16x8*)(xf + kk * 64);
                accA0 = __builtin_amdgcn_mfma_f32_16x16x32_bf16(w[0][kk], bf, accA0, 0, 0, 0);
                accA1 = __builtin_amdgcn_mfma_f32_16x16x32_bf16(w[1][kk], bf, accA1, 0, 0, 0);
            }
        }

        // stage x_{t+2} into the x buffer freed by phase A (own quarter)
        if (t + 2 < SEQ) {
            const int xoff = (t & 1) ? 768 : 0;    // (t+2)&1 == t&1
            #pragma unroll
            for (int i = 0; i < 3; ++i) {
                int ch = tid + i * 256;
                int row = ch / 48, c8 = ch % 48;
                *(uint4*)(Bs + row * LROW + xoff + c8 * 16) =
                    *(const uint4*)&xb[((size_t)(t + 2) * BATCH + bbase + row) * 384 + c8 * 8];
            }
        }

        // poll ONLY this wave's 6 producer WGs x 4 waves (lanes 0..23)
        if (lane < 24) {
            while (__hip_atomic_load(pollflag, __ATOMIC_RELAXED,
                                     __HIP_MEMORY_SCOPE_AGENT) < (unsigned)(t + 1)) {
            }
        }

        // load own h quarter: 16 rows x 48 u64 (du in [48*wv, 48*wv+48))
        unsigned long long v[12];
        {
            const unsigned long long* src64 =
                (const unsigned long long*)xh32 + (size_t)(t & 1) * BATCH * 192;
            #pragma unroll
            for (int i = 0; i < 12; ++i) {
                int idx = lane + i * 64;           // 0..767
                int row = idx / 48, du = wv * 48 + idx % 48;
                v[i] = __hip_atomic_load(&src64[(size_t)(bbase + row) * 192 + du],
                                         __ATOMIC_RELAXED, __HIP_MEMORY_SCOPE_AGENT);
            }
        }

        __syncthreads();   // (a) all waves' phase-B reads done -> h WAR safe

        #pragma unroll
        for (int i = 0; i < 12; ++i) {
            int idx = lane + i * 64;
            int row = idx / 48, du = wv * 48 + idx % 48;
            *(unsigned long long*)(Bs + row * LROW + HOFF + du * 8) = v[i];
        }
        __syncthreads();   // (b) new h visible to all waves
    }
}

// ---------------------------------------------------------------------------
extern "C" void kernel_launch(void* const* d_in, const int* in_sizes, int n_in,
                              void* d_out, int out_size, void* d_ws, size_t ws_size,
                              hipStream_t stream) {
    (void)in_sizes; (void)n_in; (void)out_size; (void)ws_size;
    const float* x    = (const float*)d_in[0];
    const float* h0   = (const float*)d_in[1];
    const float* c0   = (const float*)d_in[2];
    const float* W    = (const float*)d_in[3];
    const float* U    = (const float*)d_in[4];
    const float* bias = (const float*)d_in[5];
    const float* G    = (const float*)d_in[6];
    float* out = (float*)d_out;

    char* wsb = (char*)d_ws;
    unsigned* bar = (unsigned*)wsb;                                    // 64 KB
    __bf16* VmT  = (__bf16*)(wsb + 65536);                             // 6.75 MB
    __bf16* xb   = (__bf16*)(wsb + 65536 + (size_t)GATES * KV * 2);    // 12.6 MB
    unsigned* xh32 = (unsigned*)(wsb + 65536 + (size_t)GATES * KV * 2
                                      + (size_t)SEQ * BATCH * 384 * 2);   // 393 KB

    hipMemsetAsync(bar, 0, 65536, stream);
    prep_kernel<<<dim3(18, 48), 256, 0, stream>>>(W, U, G, VmT);
    prep_x<<<dim3(3072), 256, 0, stream>>>(x, xb);
    scan_kernel<<<dim3(NWG), dim3(256), 0, stream>>>(xb, h0, c0, VmT, bias,
                                                     out, xh32, bar);
}